// Round 7
// baseline (29.901 us; speedup 1.0000x reference)
//
#include <hip/hip_runtime.h>
#include <math.h>

// out_j = sum_{kk,ll < NF} P[ll,kk] cos(kk x_j) cos(ll y_j)
//                        + Q[ll,kk] sin(kk x_j) sin(ll y_j)
// NF=24 truncation of the exp(-0.02 f^2)-weighted folded 128x128 grid.
// PQ rows are 256 B slots: P half at +0 (24 floats), Q half at +128 B.
// Rows are fetched with explicit s_load_dwordx16/x8 (SMEM pipe, broadcast
// via SGPR operand of v_fmac). Each thread evaluates TWO points so every
// fetched half-row feeds ~50 FMAs before its lgkmcnt(0) drain.

#define NF 24
#define RSTR 64            // floats per row slot (256 B)
#define NPQ (NF * NF)
#define BLOCK 256

typedef int v16i __attribute__((ext_vector_type(16)));
typedef int v8i  __attribute__((ext_vector_type(8)));

#define SLOAD_HALF(d16, d8, ptr)                                   \
    asm volatile("s_load_dwordx16 %0, %2, 0\n\t"                   \
                 "s_load_dwordx8  %1, %2, 64"                      \
                 : "=&s"(d16), "=&s"(d8) : "s"(ptr))

#define SWAIT(d16, d8)                                             \
    asm volatile("s_waitcnt lgkmcnt(0)" : "+s"(d16), "+s"(d8))

__device__ __forceinline__ float elt(const v16i& a, const v8i& b, int k) {
    return __int_as_float(k < 16 ? a[k] : b[k - 16]);
}

__global__ void fold_pq(const float* __restrict__ coef, float* __restrict__ PQ)
{
    int t = blockIdx.x * blockDim.x + threadIdx.x;
    if (t >= NPQ) return;
    int ll = t / NF;
    int kk = t - ll * NF;
    float Pv = 0.f, Qv = 0.f;
    int   iv[2]; float isg[2]; int ni;
    iv[0] = 64 - kk; isg[0] = (kk == 0) ? 0.f : -1.f; ni = 1;
    if (kk >= 1) { iv[1] = 64 + kk; isg[1] = 1.f; ni = 2; }
    int   jv[2]; float jsg[2]; int nj;
    jv[0] = 64 - ll; jsg[0] = (ll == 0) ? 0.f : -1.f; nj = 1;
    if (ll >= 1) { jv[1] = 64 + ll; jsg[1] = 1.f; nj = 2; }
    for (int a = 0; a < ni; ++a) {
        for (int b = 0; b < nj; ++b) {
            int i = iv[a], j = jv[b];
            float fx = (float)(i - 64), fy = (float)(j - 64);
            float w  = expf(-0.02f * (fx * fx + fy * fy));
            float cw = coef[(i << 7) + j] * w;
            Pv += cw;
            Qv -= isg[a] * jsg[b] * cw;
        }
    }
    PQ[ll * RSTR + kk]      = Pv;
    PQ[ll * RSTR + 32 + kk] = Qv;
}

__global__ __launch_bounds__(BLOCK, 2)
void fouriergp_eval(const float* __restrict__ PQ,
                    const float* __restrict__ xs,
                    const float* __restrict__ ys,
                    float* __restrict__ out, int M)
{
    int half = M >> 1;
    int j0 = blockIdx.x * BLOCK + threadIdx.x;   // grid covers [0, M/2)
    if (j0 >= half) j0 = half - 1;
    int j1 = j0 + half;

    float x0 = xs[j0], y0 = ys[j0];
    float x1 = xs[j1], y1 = ys[j1];

    float cA1, sA1; sincosf(x0, &sA1, &cA1);
    float cB1, sB1; sincosf(y0, &sB1, &cB1);
    float cC1, sC1; sincosf(x1, &sC1, &cC1);
    float cD1, sD1; sincosf(y1, &sD1, &cD1);

    // Trig tables for both points (rotation recurrence, fully unrolled).
    float cx0[NF], sx0[NF], cx1[NF], sx1[NF];
    cx0[0] = 1.f; sx0[0] = 0.f; cx0[1] = cA1; sx0[1] = sA1;
    cx1[0] = 1.f; sx1[0] = 0.f; cx1[1] = cC1; sx1[1] = sC1;
    #pragma unroll
    for (int k = 2; k < NF; ++k) {
        cx0[k] = cx0[k - 1] * cA1 - sx0[k - 1] * sA1;
        sx0[k] = sx0[k - 1] * cA1 + cx0[k - 1] * sA1;
        cx1[k] = cx1[k - 1] * cC1 - sx1[k - 1] * sC1;
        sx1[k] = sx1[k - 1] * cC1 + cx1[k - 1] * sC1;
    }

    v16i p0; v8i p1;
    v16i q0; v8i q1;
    SLOAD_HALF(p0, p1, PQ);          // prologue: P row 0
    SWAIT(p0, p1);

    float acc0 = 0.f, acc1 = 0.f;
    float cy0 = 1.f, sy0 = 0.f;      // cos(l y0), sin(l y0)
    float cy1v = 1.f, sy1v = 0.f;    // cos(l y1), sin(l y1)
    #pragma unroll 1
    for (int l = 0; l < NF; ++l) {
        const float* rq = PQ + l * RSTR + 32;
        SLOAD_HALF(q0, q1, rq);                        // issue Q_l

        float a0 = 0.f, a1 = 0.f, a2 = 0.f, a3 = 0.f;  // P_l, point 0
        float c0 = 0.f, c1r = 0.f, c2 = 0.f, c3 = 0.f; // P_l, point 1
        #pragma unroll
        for (int k = 0; k < NF; k += 4) {
            float w0 = elt(p0, p1, k),     w1 = elt(p0, p1, k + 1);
            float w2 = elt(p0, p1, k + 2), w3 = elt(p0, p1, k + 3);
            a0 = fmaf(w0, cx0[k],     a0);  c0  = fmaf(w0, cx1[k],     c0);
            a1 = fmaf(w1, cx0[k + 1], a1);  c1r = fmaf(w1, cx1[k + 1], c1r);
            a2 = fmaf(w2, cx0[k + 2], a2);  c2  = fmaf(w2, cx1[k + 2], c2);
            a3 = fmaf(w3, cx0[k + 3], a3);  c3  = fmaf(w3, cx1[k + 3], c3);
        }
        acc0 = fmaf((a0 + a1) + (a2 + a3), cy0,  acc0);
        acc1 = fmaf((c0 + c1r) + (c2 + c3), cy1v, acc1);

        SWAIT(q0, q1);                                 // drain Q_l

        const float* rp = PQ + (l + 1) * RSTR;
        SLOAD_HALF(p0, p1, rp);                        // issue P_{l+1}
        // (last iteration prefetches an unused slot inside d_ws)

        float b0 = 0.f, b1 = 0.f, b2 = 0.f, b3 = 0.f;  // Q_l, point 0
        float d0 = 0.f, d1 = 0.f, d2 = 0.f, d3 = 0.f;  // Q_l, point 1
        #pragma unroll
        for (int k = 0; k < NF; k += 4) {
            float w0 = elt(q0, q1, k),     w1 = elt(q0, q1, k + 1);
            float w2 = elt(q0, q1, k + 2), w3 = elt(q0, q1, k + 3);
            b0 = fmaf(w0, sx0[k],     b0);  d0 = fmaf(w0, sx1[k],     d0);
            b1 = fmaf(w1, sx0[k + 1], b1);  d1 = fmaf(w1, sx1[k + 1], d1);
            b2 = fmaf(w2, sx0[k + 2], b2);  d2 = fmaf(w2, sx1[k + 2], d2);
            b3 = fmaf(w3, sx0[k + 3], b3);  d3 = fmaf(w3, sx1[k + 3], d3);
        }
        acc0 = fmaf((b0 + b1) + (b2 + b3), sy0,  acc0);
        acc1 = fmaf((d0 + d1) + (d2 + d3), sy1v, acc1);

        SWAIT(p0, p1);                                 // drain P_{l+1}

        float cn0 = fmaf(cy0, cB1, -sy0 * sB1);        // advance y-rotations
        float sn0 = fmaf(sy0, cB1,  cy0 * sB1);
        cy0 = cn0; sy0 = sn0;
        float cn1 = fmaf(cy1v, cD1, -sy1v * sD1);
        float sn1 = fmaf(sy1v, cD1,  cy1v * sD1);
        cy1v = cn1; sy1v = sn1;
    }
    out[j0] = acc0;
    out[j1] = acc1;
}

extern "C" void kernel_launch(void* const* d_in, const int* in_sizes, int n_in,
                              void* d_out, int out_size, void* d_ws, size_t ws_size,
                              hipStream_t stream) {
    const float* coef = (const float*)d_in[0];
    const float* x    = (const float*)d_in[1];
    const float* y    = (const float*)d_in[2];
    float* out = (float*)d_out;
    float* PQ  = (float*)d_ws;
    int M = in_sizes[1];

    fold_pq<<<(NPQ + BLOCK - 1) / BLOCK, BLOCK, 0, stream>>>(coef, PQ);
    int halfM = M >> 1;
    fouriergp_eval<<<(halfM + BLOCK - 1) / BLOCK, BLOCK, 0, stream>>>(PQ, x, y, out, M);
}

// Round 8
// 27.848 us; speedup vs baseline: 1.0737x; 1.0737x over previous
//
#include <hip/hip_runtime.h>
#include <math.h>

// out_j = sum_{kk,ll < NF} P[ll,kk] cos(kk x_j) cos(ll y_j)
//                        + Q[ll,kk] sin(kk x_j) sin(ll y_j)
// NF=24 truncation of the exp(-0.02 f^2)-weighted folded 128x128 grid.
// PQ rows are 256 B slots: P half at +0 (24 floats), Q half at +128 B.
// k-SPLIT ACROSS WAVE PAIRS: wave parity 0 sums k=0..11, parity 1 sums
// k=12..23 (trig tables start at cos(12x),sin(12x)). Halves per-wave VGPR
// (fits 8 waves/SIMD) and doubles total waves (8192 = 8/SIMD) so the
// mandatory lgkmcnt(0) SMEM drains are hidden by TLP. Partials combine
// via 128 floats of LDS per block.

#define NF 24
#define HK 12              // k per wave parity
#define RSTR 64            // floats per row slot (256 B)
#define NPQ (NF * NF)
#define BLOCK 256

typedef int v8i __attribute__((ext_vector_type(8)));
typedef int v4i __attribute__((ext_vector_type(4)));

// load 12 floats (48 B) at ptr into s-tuples
#define SLOAD_HALF(d8, d4, ptr)                                    \
    asm volatile("s_load_dwordx8 %0, %2, 0\n\t"                    \
                 "s_load_dwordx4 %1, %2, 32"                       \
                 : "=&s"(d8), "=&s"(d4) : "s"(ptr))

// drain SMEM; dataflow through the tuples orders uses after the wait
#define SWAIT(d8, d4)                                              \
    asm volatile("s_waitcnt lgkmcnt(0)" : "+s"(d8), "+s"(d4))

__device__ __forceinline__ float elt(const v8i& a, const v4i& b, int k) {
    return __int_as_float(k < 8 ? a[k] : b[k - 8]);
}

__global__ void fold_pq(const float* __restrict__ coef, float* __restrict__ PQ)
{
    int t = blockIdx.x * blockDim.x + threadIdx.x;
    if (t >= NPQ) return;
    int ll = t / NF;
    int kk = t - ll * NF;
    float Pv = 0.f, Qv = 0.f;
    int   iv[2]; float isg[2]; int ni;
    iv[0] = 64 - kk; isg[0] = (kk == 0) ? 0.f : -1.f; ni = 1;
    if (kk >= 1) { iv[1] = 64 + kk; isg[1] = 1.f; ni = 2; }
    int   jv[2]; float jsg[2]; int nj;
    jv[0] = 64 - ll; jsg[0] = (ll == 0) ? 0.f : -1.f; nj = 1;
    if (ll >= 1) { jv[1] = 64 + ll; jsg[1] = 1.f; nj = 2; }
    for (int a = 0; a < ni; ++a) {
        for (int b = 0; b < nj; ++b) {
            int i = iv[a], j = jv[b];
            float fx = (float)(i - 64), fy = (float)(j - 64);
            float w  = expf(-0.02f * (fx * fx + fy * fy));
            float cw = coef[(i << 7) + j] * w;
            Pv += cw;
            Qv -= isg[a] * jsg[b] * cw;
        }
    }
    PQ[ll * RSTR + kk]      = Pv;
    PQ[ll * RSTR + 32 + kk] = Qv;
}

__global__ __launch_bounds__(BLOCK, 8)
void fouriergp_eval(const float* __restrict__ PQ,
                    const float* __restrict__ xs,
                    const float* __restrict__ ys,
                    float* __restrict__ out, int M)
{
    __shared__ float sPart[128];

    int wid  = threadIdx.x >> 6;        // 0..3
    int lane = threadIdx.x & 63;
    int par  = wid & 1;                 // k-parity of this wave
    int pt   = (wid >> 1) * 64 + lane;  // 0..127: point slot in block
    int j    = blockIdx.x * 128 + pt;   // M = 2048*128 exactly

    float xj = xs[j], yj = ys[j];

    // k-offset start: cos(par*12*x), sin(par*12*x); then rotate by x.
    float c1, s1;   sincosf(xj, &s1, &c1);
    float ck0, sk0; sincosf((float)(par * HK) * xj, &sk0, &ck0);
    float cy1, sy1; sincosf(yj, &sy1, &cy1);

    // Trig tables for this wave's 12 k values (rotation recurrence, VGPRs).
    float cxk[HK], sxk[HK];
    cxk[0] = ck0; sxk[0] = sk0;
    #pragma unroll
    for (int m = 1; m < HK; ++m) {
        cxk[m] = cxk[m - 1] * c1 - sxk[m - 1] * s1;
        sxk[m] = sxk[m - 1] * c1 + cxk[m - 1] * s1;
    }

    int poff = __builtin_amdgcn_readfirstlane(par * HK);

    v8i p0; v4i p1;
    v8i q0; v4i q1;
    SLOAD_HALF(p0, p1, PQ + poff);      // prologue: P row 0 (this parity's half)
    SWAIT(p0, p1);

    float acc = 0.f, cyl = 1.f, syl = 0.f;
    #pragma unroll 1
    for (int l = 0; l < NF; ++l) {
        const float* rq = PQ + l * RSTR + 32 + poff;
        SLOAD_HALF(q0, q1, rq);                        // issue Q_l half

        float a0 = 0.f, a1 = 0.f, a2 = 0.f, a3 = 0.f;  // P_l half
        #pragma unroll
        for (int k = 0; k < HK; k += 4) {
            a0 = fmaf(elt(p0, p1, k),     cxk[k],     a0);
            a1 = fmaf(elt(p0, p1, k + 1), cxk[k + 1], a1);
            a2 = fmaf(elt(p0, p1, k + 2), cxk[k + 2], a2);
            a3 = fmaf(elt(p0, p1, k + 3), cxk[k + 3], a3);
        }
        acc = fmaf((a0 + a1) + (a2 + a3), cyl, acc);

        SWAIT(q0, q1);                                 // drain Q_l

        const float* rp = PQ + (l + 1) * RSTR + poff;
        SLOAD_HALF(p0, p1, rp);                        // issue P_{l+1} half
        // (last iteration prefetches an unused slot inside d_ws)

        float b0 = 0.f, b1 = 0.f, b2 = 0.f, b3 = 0.f;  // Q_l half
        #pragma unroll
        for (int k = 0; k < HK; k += 4) {
            b0 = fmaf(elt(q0, q1, k),     sxk[k],     b0);
            b1 = fmaf(elt(q0, q1, k + 1), sxk[k + 1], b1);
            b2 = fmaf(elt(q0, q1, k + 2), sxk[k + 2], b2);
            b3 = fmaf(elt(q0, q1, k + 3), sxk[k + 3], b3);
        }
        acc = fmaf((b0 + b1) + (b2 + b3), syl, acc);

        SWAIT(p0, p1);                                 // drain P_{l+1}

        float cn = fmaf(cyl, cy1, -syl * sy1);         // advance y-rotation
        float sn = fmaf(syl, cy1,  cyl * sy1);
        cyl = cn; syl = sn;
    }

    // combine the two k-halves of each point through LDS
    if (par == 1) sPart[pt] = acc;
    __syncthreads();
    if (par == 0) out[j] = acc + sPart[pt];
}

extern "C" void kernel_launch(void* const* d_in, const int* in_sizes, int n_in,
                              void* d_out, int out_size, void* d_ws, size_t ws_size,
                              hipStream_t stream) {
    const float* coef = (const float*)d_in[0];
    const float* x    = (const float*)d_in[1];
    const float* y    = (const float*)d_in[2];
    float* out = (float*)d_out;
    float* PQ  = (float*)d_ws;
    int M = in_sizes[1];

    fold_pq<<<(NPQ + BLOCK - 1) / BLOCK, BLOCK, 0, stream>>>(coef, PQ);
    int blocks = M / 128;               // 2048 for M=262144
    fouriergp_eval<<<blocks, BLOCK, 0, stream>>>(PQ, x, y, out, M);
}

// Round 9
// 21.010 us; speedup vs baseline: 1.4232x; 1.3255x over previous
//
#include <hip/hip_runtime.h>
#include <math.h>

// out_j = sum_{k,l<NF} P[l,k] cos(k x_j) cos(l y_j) + Q[l,k] sin(k x_j) sin(l y_j)
// NF=24 truncation (weight exp(-0.02 f^2) < 1e-5 beyond).
// MFMA formulation: per 16-point tile,
//   T[j,l] = sum_k P[l,k] cos(k x_j)   (2x mfma 16x16x32 bf16, l-tiles 0..15/16..31)
//   U[j,l] = sum_k Q[l,k] sin(k x_j)   (2x mfma)
// then out_j = sum_l T*cos(l y_j) + U*sin(l y_j) via HW v_cos/v_sin (revolutions)
// and a 16-lane shfl reduction. B fragments (P/Q) live in VGPRs for the whole
// kernel -- no broadcast loads, no SMEM drains.

#define NF 24
#define RSTR 64            // floats per row slot (256 B): P at +0, Q at +32
#define NPQ (NF * NF)
#define BLOCK 256
#define TILES 4            // 16-point tiles per wave -> 256 points per block

typedef __attribute__((ext_vector_type(8))) short bf16x8;
typedef __attribute__((ext_vector_type(4))) float f32x4;

static __device__ __forceinline__ unsigned short bf16rne(float f) {
    unsigned int u = __float_as_uint(f);
    u += 0x7FFFu + ((u >> 16) & 1u);
    return (unsigned short)(u >> 16);
}
static __device__ __forceinline__ float fract_(float t) { return t - floorf(t); }

__global__ void fold_pq(const float* __restrict__ coef, float* __restrict__ PQ)
{
    int t = blockIdx.x * blockDim.x + threadIdx.x;
    if (t >= NPQ) return;
    int ll = t / NF;
    int kk = t - ll * NF;
    float Pv = 0.f, Qv = 0.f;
    int   iv[2]; float isg[2]; int ni;
    iv[0] = 64 - kk; isg[0] = (kk == 0) ? 0.f : -1.f; ni = 1;
    if (kk >= 1) { iv[1] = 64 + kk; isg[1] = 1.f; ni = 2; }
    int   jv[2]; float jsg[2]; int nj;
    jv[0] = 64 - ll; jsg[0] = (ll == 0) ? 0.f : -1.f; nj = 1;
    if (ll >= 1) { jv[1] = 64 + ll; jsg[1] = 1.f; nj = 2; }
    for (int a = 0; a < ni; ++a) {
        for (int b = 0; b < nj; ++b) {
            int i = iv[a], j = jv[b];
            float fx = (float)(i - 64), fy = (float)(j - 64);
            float w  = expf(-0.02f * (fx * fx + fy * fy));
            float cw = coef[(i << 7) + j] * w;
            Pv += cw;
            Qv -= isg[a] * jsg[b] * cw;
        }
    }
    PQ[ll * RSTR + kk]      = Pv;
    PQ[ll * RSTR + 32 + kk] = Qv;
}

__global__ __launch_bounds__(BLOCK, 4)
void fouriergp_eval(const float* __restrict__ PQ,
                    const float* __restrict__ xs,
                    const float* __restrict__ ys,
                    float* __restrict__ out, int M)
{
    const float inv2pi = 0.15915494309189535f;
    int wid  = threadIdx.x >> 6;
    int lane = threadIdx.x & 63;
    int g    = lane >> 4;    // k-group (A/B), row-group (C)
    int n    = lane & 15;    // point index in A; l index in B/C

    // ---- B fragments: B[k,l] = P[l,k] (or Q[l,k]); k = g*8+e, col l.
    // Loaded once; out-of-range (k>=24 or l>=24) slots masked to 0.
    bf16x8 bP0, bP1, bQ0, bQ1;
#define LOADB(dst, lrow, qoff)                                        \
    {                                                                 \
        int l_ = (lrow);                                              \
        const float* bp = PQ + l_ * RSTR + (qoff) + g * 8;            \
        float4 v0 = *(const float4*)(bp);                             \
        float4 v1 = *(const float4*)(bp + 4);                         \
        float vv[8] = {v0.x, v0.y, v0.z, v0.w, v1.x, v1.y, v1.z, v1.w}; \
        _Pragma("unroll")                                             \
        for (int e = 0; e < 8; ++e) {                                 \
            int k_ = g * 8 + e;                                       \
            float val = (k_ < NF && l_ < NF) ? vv[e] : 0.f;           \
            dst[e] = (short)bf16rne(val);                             \
        }                                                             \
    }
    LOADB(bP0, n,      0)
    LOADB(bP1, n + 16, 0)
    LOADB(bQ0, n,      32)
    LOADB(bQ1, n + 16, 32)
#undef LOADB

    int jb0 = blockIdx.x * ((BLOCK / 64) * TILES * 16) + wid * (TILES * 16);
    #pragma unroll 1
    for (int t = 0; t < TILES; ++t) {
        int jb = jb0 + t * 16;

        // A fragments: A[m,k] = cos/sin(k * x_m); m = n, k = g*8+e.
        float xv = xs[jb + n];
        float tx = xv * inv2pi;
        bf16x8 aC, aS;
        #pragma unroll
        for (int e = 0; e < 8; ++e) {
            float tt = fract_((float)(g * 8 + e) * tx);
            float cv = __builtin_amdgcn_cosf(tt);
            float sv = __builtin_amdgcn_sinf(tt);
            aC[e] = (short)bf16rne(cv);
            aS[e] = (short)bf16rne(sv);
        }

        f32x4 z = {0.f, 0.f, 0.f, 0.f};
        f32x4 T0 = __builtin_amdgcn_mfma_f32_16x16x32_bf16(aC, bP0, z, 0, 0, 0);
        f32x4 T1 = __builtin_amdgcn_mfma_f32_16x16x32_bf16(aC, bP1, z, 0, 0, 0);
        f32x4 U0 = __builtin_amdgcn_mfma_f32_16x16x32_bf16(aS, bQ0, z, 0, 0, 0);
        f32x4 U1 = __builtin_amdgcn_mfma_f32_16x16x32_bf16(aS, bQ1, z, 0, 0, 0);

        // Epilogue: C[row=g*4+r, col=n] -> point p = g*4+r, l in {n, n+16}.
        float o[4];
        float l0 = (float)n, l1 = (float)(n + 16);
        #pragma unroll
        for (int r = 0; r < 4; ++r) {
            float yv = ys[jb + g * 4 + r];
            float ty = yv * inv2pi;
            float t0 = fract_(l0 * ty);
            float t1 = fract_(l1 * ty);
            float c0 = __builtin_amdgcn_cosf(t0);
            float s0 = __builtin_amdgcn_sinf(t0);
            float c1 = __builtin_amdgcn_cosf(t1);
            float s1 = __builtin_amdgcn_sinf(t1);
            o[r] = fmaf(T0[r], c0, fmaf(U0[r], s0,
                   fmaf(T1[r], c1, U1[r] * s1)));
        }

        // Reduce over the 16 l-lanes (same g); then lane n==0 stores 4 points.
        #pragma unroll
        for (int m = 1; m < 16; m <<= 1) {
            #pragma unroll
            for (int r = 0; r < 4; ++r) o[r] += __shfl_xor(o[r], m, 64);
        }
        if (n == 0) {
            #pragma unroll
            for (int r = 0; r < 4; ++r) out[jb + g * 4 + r] = o[r];
        }
    }
}

extern "C" void kernel_launch(void* const* d_in, const int* in_sizes, int n_in,
                              void* d_out, int out_size, void* d_ws, size_t ws_size,
                              hipStream_t stream) {
    const float* coef = (const float*)d_in[0];
    const float* x    = (const float*)d_in[1];
    const float* y    = (const float*)d_in[2];
    float* out = (float*)d_out;
    float* PQ  = (float*)d_ws;
    int M = in_sizes[1];

    fold_pq<<<(NPQ + BLOCK - 1) / BLOCK, BLOCK, 0, stream>>>(coef, PQ);
    int blocks = M / ((BLOCK / 64) * TILES * 16);   // 1024 for M=262144
    fouriergp_eval<<<blocks, BLOCK, 0, stream>>>(PQ, x, y, out, M);
}

// Round 10
// 16.918 us; speedup vs baseline: 1.7674x; 1.2419x over previous
//
#include <hip/hip_runtime.h>
#include <hip/hip_bf16.h>
#include <math.h>

// out_j = sum_{k,l<NF} P[l,k] cos(k x_j) cos(l y_j) + Q[l,k] sin(k x_j) sin(l y_j)
// NF=24 truncation (spectral weight exp(-0.02 f^2) < 1e-5 beyond).
// SINGLE fused kernel:
//  1) block-cooperative fold of the weighted 128x128 coefficient grid into
//     LDS P/Q[l][k] (l,k < 32, zero-padded past NF; row stride 68 = bank-safe)
//  2) per 16-point tile: T[j,l] = sum_k P[l,k] cos(k x_j) via
//     mfma_f32_16x16x32_bf16 (B fragments in VGPRs for the whole kernel),
//     epilogue sum_l T*cos(l y) + U*sin(l y) with HW v_cos/v_sin (revolutions)
//     and a 16-lane shfl_xor reduction; lane n==0 stores a float4.

#define NF 24
#define LSTR 68            // LDS row stride in floats (bank-spread, 16B-aligned)
#define BLOCK 256
#define TILES 4            // 16-pt tiles per wave -> 256 points per block

typedef __attribute__((ext_vector_type(8))) short bf16x8;
typedef __attribute__((ext_vector_type(4))) float f32x4;

union BF8 { bf16x8 v; __hip_bfloat162 h[4]; };

static __device__ __forceinline__ float fract_(float t) { return t - floorf(t); }

__global__ __launch_bounds__(BLOCK, 4)
void fouriergp_fused(const float* __restrict__ coef,
                     const float* __restrict__ xs,
                     const float* __restrict__ ys,
                     float* __restrict__ out, int M)
{
    __shared__ float sP[32 * LSTR];
    __shared__ float sQ[32 * LSTR];

    // ---- 1) cooperative fold into LDS (zero-padded to 32x32) ----
    for (int t = threadIdx.x; t < 32 * 32; t += BLOCK) {
        int ll = t >> 5, kk = t & 31;
        float Pv = 0.f, Qv = 0.f;
        if (ll < NF && kk < NF) {
            int   iv[2]; float isg[2]; int ni;
            iv[0] = 64 - kk; isg[0] = (kk == 0) ? 0.f : -1.f; ni = 1;
            if (kk >= 1) { iv[1] = 64 + kk; isg[1] = 1.f; ni = 2; }
            int   jv[2]; float jsg[2]; int nj;
            jv[0] = 64 - ll; jsg[0] = (ll == 0) ? 0.f : -1.f; nj = 1;
            if (ll >= 1) { jv[1] = 64 + ll; jsg[1] = 1.f; nj = 2; }
            for (int a = 0; a < ni; ++a) {
                for (int b = 0; b < nj; ++b) {
                    int i = iv[a], j = jv[b];
                    float fx = (float)(i - 64), fy = (float)(j - 64);
                    float w  = expf(-0.02f * (fx * fx + fy * fy));
                    float cw = coef[(i << 7) + j] * w;
                    Pv += cw;
                    Qv -= isg[a] * jsg[b] * cw;
                }
            }
        }
        sP[ll * LSTR + kk] = Pv;
        sQ[ll * LSTR + kk] = Qv;
    }
    __syncthreads();

    // ---- 2) MFMA evaluation ----
    const float inv2pi = 0.15915494309189535f;
    int wid  = threadIdx.x >> 6;
    int lane = threadIdx.x & 63;
    int g    = lane >> 4;    // k-group (A/B), row-group (C)
    int n    = lane & 15;    // point index in A; l (column) index in B/C

    // B fragments: B[k=g*8+e, col=l] = P[l,k]; rows l = n and n+16.
    BF8 bP0, bP1, bQ0, bQ1;
#define LOADB(dst, arr, l_)                                             \
    {                                                                   \
        const float* bp = &arr[(l_) * LSTR + g * 8];                    \
        float4 v0 = *(const float4*)bp;                                 \
        float4 v1 = *(const float4*)(bp + 4);                           \
        dst.h[0] = __float22bfloat162_rn(float2{v0.x, v0.y});           \
        dst.h[1] = __float22bfloat162_rn(float2{v0.z, v0.w});           \
        dst.h[2] = __float22bfloat162_rn(float2{v1.x, v1.y});           \
        dst.h[3] = __float22bfloat162_rn(float2{v1.z, v1.w});           \
    }
    LOADB(bP0, sP, n)
    LOADB(bP1, sP, n + 16)
    LOADB(bQ0, sQ, n)
    LOADB(bQ1, sQ, n + 16)
#undef LOADB

    int jb0 = blockIdx.x * ((BLOCK / 64) * TILES * 16) + wid * (TILES * 16);
    #pragma unroll 1
    for (int t = 0; t < TILES; ++t) {
        int jb = jb0 + t * 16;

        // A fragments: A[m=n, k=g*8+e] = cos/sin(k * x_n) (HW trig, revolutions).
        float tx = xs[jb + n] * inv2pi;
        float cv[8], sv[8];
        #pragma unroll
        for (int e = 0; e < 8; ++e) {
            float tt = fract_((float)(g * 8 + e) * tx);
            cv[e] = __builtin_amdgcn_cosf(tt);
            sv[e] = __builtin_amdgcn_sinf(tt);
        }
        BF8 aC, aS;
        #pragma unroll
        for (int e = 0; e < 4; ++e) {
            aC.h[e] = __float22bfloat162_rn(float2{cv[2 * e], cv[2 * e + 1]});
            aS.h[e] = __float22bfloat162_rn(float2{sv[2 * e], sv[2 * e + 1]});
        }

        f32x4 z = {0.f, 0.f, 0.f, 0.f};
        f32x4 T0 = __builtin_amdgcn_mfma_f32_16x16x32_bf16(aC.v, bP0.v, z, 0, 0, 0);
        f32x4 T1 = __builtin_amdgcn_mfma_f32_16x16x32_bf16(aC.v, bP1.v, z, 0, 0, 0);
        f32x4 U0 = __builtin_amdgcn_mfma_f32_16x16x32_bf16(aS.v, bQ0.v, z, 0, 0, 0);
        f32x4 U1 = __builtin_amdgcn_mfma_f32_16x16x32_bf16(aS.v, bQ1.v, z, 0, 0, 0);

        // Epilogue: C[row=g*4+r, col=n] -> point g*4+r, l in {n, n+16}.
        float o[4];
        float l0 = (float)n, l1 = (float)(n + 16);
        #pragma unroll
        for (int r = 0; r < 4; ++r) {
            float ty = ys[jb + g * 4 + r] * inv2pi;
            float c0 = __builtin_amdgcn_cosf(fract_(l0 * ty));
            float s0 = __builtin_amdgcn_sinf(fract_(l0 * ty));
            float c1 = __builtin_amdgcn_cosf(fract_(l1 * ty));
            float s1 = __builtin_amdgcn_sinf(fract_(l1 * ty));
            o[r] = fmaf(T0[r], c0, fmaf(U0[r], s0,
                   fmaf(T1[r], c1, U1[r] * s1)));
        }

        // Reduce over the 16 l-lanes (same g).
        #pragma unroll
        for (int m = 1; m < 16; m <<= 1) {
            #pragma unroll
            for (int r = 0; r < 4; ++r) o[r] += __shfl_xor(o[r], m, 64);
        }
        if (n == 0) {
            float4 res = make_float4(o[0], o[1], o[2], o[3]);
            *(float4*)&out[jb + g * 4] = res;
        }
    }
}

extern "C" void kernel_launch(void* const* d_in, const int* in_sizes, int n_in,
                              void* d_out, int out_size, void* d_ws, size_t ws_size,
                              hipStream_t stream) {
    const float* coef = (const float*)d_in[0];
    const float* x    = (const float*)d_in[1];
    const float* y    = (const float*)d_in[2];
    float* out = (float*)d_out;
    int M = in_sizes[1];
    int blocks = M / ((BLOCK / 64) * TILES * 16);   // 1024 for M=262144
    fouriergp_fused<<<blocks, BLOCK, 0, stream>>>(coef, x, y, out, M);
}

// Round 11
// 16.381 us; speedup vs baseline: 1.8254x; 1.0328x over previous
//
#include <hip/hip_runtime.h>
#include <hip/hip_bf16.h>
#include <math.h>

// out_j = sum_{k,l<NF} P[l,k] cos(k x_j) cos(l y_j) + Q[l,k] sin(k x_j) sin(l y_j)
// NF=24 truncation (spectral weight exp(-0.02 f^2) < 1e-5 beyond).
// Single fused kernel:
//  1) block-cooperative fold of the weighted 128x128 coefficient grid into
//     LDS P/Q[l][k] (zero-padded to 32x32; row stride 68 = bank-safe).
//     Weight is identical for all 4 sign-quadrant terms -> one expf per item.
//  2) per 16-point tile: T[j,l] = sum_k P[l,k] cos(k x_j) via
//     mfma_f32_16x16x32_bf16 (B fragments in VGPRs for the whole kernel),
//     epilogue sum_l T*cos(l y) + U*sin(l y) with HW v_cos/v_sin (revolutions)
//     + 16-lane shfl_xor reduce. All x/y loads hoisted ahead of the fully
//     unrolled tile loop so VMEM latency is paid once.

#define NF 24
#define LSTR 68            // LDS row stride in floats (bank-spread, 16B-aligned)
#define BLOCK 256
#define TILES 4            // 16-pt tiles per wave -> 256 points per block

typedef __attribute__((ext_vector_type(8))) short bf16x8;
typedef __attribute__((ext_vector_type(4))) float f32x4;

union BF8 { bf16x8 v; __hip_bfloat162 h[4]; };

static __device__ __forceinline__ float fract_(float t) { return t - floorf(t); }

__global__ __launch_bounds__(BLOCK, 4)
void fouriergp_fused(const float* __restrict__ coef,
                     const float* __restrict__ xs,
                     const float* __restrict__ ys,
                     float* __restrict__ out, int M)
{
    __shared__ float sP[32 * LSTR];
    __shared__ float sQ[32 * LSTR];

    // ---- 1) cooperative fold into LDS (zero-padded to 32x32) ----
    for (int t = threadIdx.x; t < 32 * 32; t += BLOCK) {
        int ll = t >> 5, kk = t & 31;
        float Pv = 0.f, Qv = 0.f;
        if (ll < NF && kk < NF) {
            // all four quadrant entries share |i-64|=kk, |j-64|=ll -> one weight
            float w = expf(-0.02f * (float)(kk * kk + ll * ll));
            int   iv[2]; float isg[2]; int ni;
            iv[0] = 64 - kk; isg[0] = (kk == 0) ? 0.f : -1.f; ni = 1;
            if (kk >= 1) { iv[1] = 64 + kk; isg[1] = 1.f; ni = 2; }
            int   jv[2]; float jsg[2]; int nj;
            jv[0] = 64 - ll; jsg[0] = (ll == 0) ? 0.f : -1.f; nj = 1;
            if (ll >= 1) { jv[1] = 64 + ll; jsg[1] = 1.f; nj = 2; }
            float s1 = 0.f, s2 = 0.f;
            for (int a = 0; a < ni; ++a) {
                for (int b = 0; b < nj; ++b) {
                    float c = coef[(iv[a] << 7) + jv[b]];
                    s1 += c;
                    s2 += isg[a] * jsg[b] * c;
                }
            }
            Pv = w * s1;
            Qv = -w * s2;
        }
        sP[ll * LSTR + kk] = Pv;
        sQ[ll * LSTR + kk] = Qv;
    }

    // ---- hoisted point loads (issue before the sync; used after) ----
    const float inv2pi = 0.15915494309189535f;
    int wid  = threadIdx.x >> 6;
    int lane = threadIdx.x & 63;
    int g    = lane >> 4;    // k-group (A/B), row-group (C)
    int n    = lane & 15;    // point index in A; l (column) index in B/C

    int jb0 = blockIdx.x * ((BLOCK / 64) * TILES * 16) + wid * (TILES * 16);
    float xv[TILES], yv[TILES][4];
    #pragma unroll
    for (int t = 0; t < TILES; ++t) {
        xv[t] = xs[jb0 + t * 16 + n];
        #pragma unroll
        for (int r = 0; r < 4; ++r)
            yv[t][r] = ys[jb0 + t * 16 + g * 4 + r];
    }

    __syncthreads();

    // B fragments: B[k=g*8+e, col=l] = P[l,k]; rows l = n and n+16.
    BF8 bP0, bP1, bQ0, bQ1;
#define LOADB(dst, arr, l_)                                             \
    {                                                                   \
        const float* bp = &arr[(l_) * LSTR + g * 8];                    \
        float4 v0 = *(const float4*)bp;                                 \
        float4 v1 = *(const float4*)(bp + 4);                           \
        dst.h[0] = __float22bfloat162_rn(float2{v0.x, v0.y});           \
        dst.h[1] = __float22bfloat162_rn(float2{v0.z, v0.w});           \
        dst.h[2] = __float22bfloat162_rn(float2{v1.x, v1.y});           \
        dst.h[3] = __float22bfloat162_rn(float2{v1.z, v1.w});           \
    }
    LOADB(bP0, sP, n)
    LOADB(bP1, sP, n + 16)
    LOADB(bQ0, sQ, n)
    LOADB(bQ1, sQ, n + 16)
#undef LOADB

    #pragma unroll
    for (int t = 0; t < TILES; ++t) {
        int jb = jb0 + t * 16;

        // A fragments: A[m=n, k=g*8+e] = cos/sin(k * x_n) (HW trig, revolutions).
        float tx = xv[t] * inv2pi;
        float cv[8], sv[8];
        #pragma unroll
        for (int e = 0; e < 8; ++e) {
            float tt = fract_((float)(g * 8 + e) * tx);
            cv[e] = __builtin_amdgcn_cosf(tt);
            sv[e] = __builtin_amdgcn_sinf(tt);
        }
        BF8 aC, aS;
        #pragma unroll
        for (int e = 0; e < 4; ++e) {
            aC.h[e] = __float22bfloat162_rn(float2{cv[2 * e], cv[2 * e + 1]});
            aS.h[e] = __float22bfloat162_rn(float2{sv[2 * e], sv[2 * e + 1]});
        }

        f32x4 z = {0.f, 0.f, 0.f, 0.f};
        f32x4 T0 = __builtin_amdgcn_mfma_f32_16x16x32_bf16(aC.v, bP0.v, z, 0, 0, 0);
        f32x4 T1 = __builtin_amdgcn_mfma_f32_16x16x32_bf16(aC.v, bP1.v, z, 0, 0, 0);
        f32x4 U0 = __builtin_amdgcn_mfma_f32_16x16x32_bf16(aS.v, bQ0.v, z, 0, 0, 0);
        f32x4 U1 = __builtin_amdgcn_mfma_f32_16x16x32_bf16(aS.v, bQ1.v, z, 0, 0, 0);

        // Epilogue: C[row=g*4+r, col=n] -> point g*4+r, l in {n, n+16}.
        float o[4];
        float l0 = (float)n, l1 = (float)(n + 16);
        #pragma unroll
        for (int r = 0; r < 4; ++r) {
            float ty = yv[t][r] * inv2pi;
            float c0 = __builtin_amdgcn_cosf(fract_(l0 * ty));
            float s0 = __builtin_amdgcn_sinf(fract_(l0 * ty));
            float c1 = __builtin_amdgcn_cosf(fract_(l1 * ty));
            float s1 = __builtin_amdgcn_sinf(fract_(l1 * ty));
            o[r] = fmaf(T0[r], c0, fmaf(U0[r], s0,
                   fmaf(T1[r], c1, U1[r] * s1)));
        }

        // Reduce over the 16 l-lanes (same g).
        #pragma unroll
        for (int m = 1; m < 16; m <<= 1) {
            #pragma unroll
            for (int r = 0; r < 4; ++r) o[r] += __shfl_xor(o[r], m, 64);
        }
        if (n == 0) {
            float4 res = make_float4(o[0], o[1], o[2], o[3]);
            *(float4*)&out[jb + g * 4] = res;
        }
    }
}

extern "C" void kernel_launch(void* const* d_in, const int* in_sizes, int n_in,
                              void* d_out, int out_size, void* d_ws, size_t ws_size,
                              hipStream_t stream) {
    const float* coef = (const float*)d_in[0];
    const float* x    = (const float*)d_in[1];
    const float* y    = (const float*)d_in[2];
    float* out = (float*)d_out;
    int M = in_sizes[1];
    int blocks = M / ((BLOCK / 64) * TILES * 16);   // 1024 for M=262144
    fouriergp_fused<<<blocks, BLOCK, 0, stream>>>(coef, x, y, out, M);
}

// Round 12
// 14.200 us; speedup vs baseline: 2.1057x; 1.1536x over previous
//
#include <hip/hip_runtime.h>
#include <hip/hip_bf16.h>
#include <math.h>

// out_j = sum_{k,l<NF} P[l,k] cos(k x_j) cos(l y_j) + Q[l,k] sin(k x_j) sin(l y_j)
// NF=24 truncation (spectral weight exp(-0.02 f^2) < 1e-5 beyond).
// Single fused kernel:
//  1) block-cooperative fold of the weighted 128x128 coefficient grid into
//     LDS P/Q[l][k] (zero-padded to 32x32; row stride 68). Item mapping is
//     TRANSPOSED (lane varies ll -> consecutive j addresses) so the four
//     quadrant loads are coalesced 128B segments instead of 512B-stride
//     scatter (which cost ~7us of L2 line traffic across 1024 blocks).
//  2) per 16-point tile: T[j,l] = sum_k P[l,k] cos(k x_j) via
//     mfma_f32_16x16x32_bf16 (B fragments live in VGPRs), epilogue
//     sum_l T*cos(l y) + U*sin(l y) with HW v_cos/v_sin (revolutions)
//     + 16-lane shfl_xor reduce; lane n==0 stores a float4.

#define NF 24
#define LSTR 68            // LDS row stride in floats (16B-aligned)
#define BLOCK 256
#define TILES 4            // 16-pt tiles per wave -> 256 points per block

typedef __attribute__((ext_vector_type(8))) short bf16x8;
typedef __attribute__((ext_vector_type(4))) float f32x4;

union BF8 { bf16x8 v; __hip_bfloat162 h[4]; };

static __device__ __forceinline__ float fract_(float t) { return t - floorf(t); }

__global__ __launch_bounds__(BLOCK, 4)
void fouriergp_fused(const float* __restrict__ coef,
                     const float* __restrict__ xs,
                     const float* __restrict__ ys,
                     float* __restrict__ out, int M)
{
    __shared__ float sP[32 * LSTR];
    __shared__ float sQ[32 * LSTR];

    // ---- 1) cooperative fold into LDS (zero-padded to 32x32) ----
    // Transposed mapping: lane index varies ll (column j) -> coalesced loads.
    for (int t = threadIdx.x; t < 32 * 32; t += BLOCK) {
        int kk = t >> 5, ll = t & 31;
        float Pv = 0.f, Qv = 0.f;
        if (ll < NF && kk < NF) {
            // all four quadrant entries share |i-64|=kk, |j-64|=ll -> one weight
            float w = expf(-0.02f * (float)(kk * kk + ll * ll));
            int   iv[2]; float isg[2]; int ni;
            iv[0] = 64 - kk; isg[0] = (kk == 0) ? 0.f : -1.f; ni = 1;
            if (kk >= 1) { iv[1] = 64 + kk; isg[1] = 1.f; ni = 2; }
            int   jv[2]; float jsg[2]; int nj;
            jv[0] = 64 - ll; jsg[0] = (ll == 0) ? 0.f : -1.f; nj = 1;
            if (ll >= 1) { jv[1] = 64 + ll; jsg[1] = 1.f; nj = 2; }
            float s1 = 0.f, s2 = 0.f;
            for (int a = 0; a < ni; ++a) {
                for (int b = 0; b < nj; ++b) {
                    float c = coef[(iv[a] << 7) + jv[b]];
                    s1 += c;
                    s2 += isg[a] * jsg[b] * c;
                }
            }
            Pv = w * s1;
            Qv = -w * s2;
        }
        sP[ll * LSTR + kk] = Pv;
        sQ[ll * LSTR + kk] = Qv;
    }

    // ---- hoisted point loads (issue before the sync; used after) ----
    const float inv2pi = 0.15915494309189535f;
    int wid  = threadIdx.x >> 6;
    int lane = threadIdx.x & 63;
    int g    = lane >> 4;    // k-group (A/B), row-group (C)
    int n    = lane & 15;    // point index in A; l (column) index in B/C

    int jb0 = blockIdx.x * ((BLOCK / 64) * TILES * 16) + wid * (TILES * 16);
    float xv[TILES], yv[TILES][4];
    #pragma unroll
    for (int t = 0; t < TILES; ++t) {
        xv[t] = xs[jb0 + t * 16 + n];
        #pragma unroll
        for (int r = 0; r < 4; ++r)
            yv[t][r] = ys[jb0 + t * 16 + g * 4 + r];
    }

    __syncthreads();

    // B fragments: B[k=g*8+e, col=l] = P[l,k]; rows l = n and n+16.
    BF8 bP0, bP1, bQ0, bQ1;
#define LOADB(dst, arr, l_)                                             \
    {                                                                   \
        const float* bp = &arr[(l_) * LSTR + g * 8];                    \
        float4 v0 = *(const float4*)bp;                                 \
        float4 v1 = *(const float4*)(bp + 4);                           \
        dst.h[0] = __float22bfloat162_rn(float2{v0.x, v0.y});           \
        dst.h[1] = __float22bfloat162_rn(float2{v0.z, v0.w});           \
        dst.h[2] = __float22bfloat162_rn(float2{v1.x, v1.y});           \
        dst.h[3] = __float22bfloat162_rn(float2{v1.z, v1.w});           \
    }
    LOADB(bP0, sP, n)
    LOADB(bP1, sP, n + 16)
    LOADB(bQ0, sQ, n)
    LOADB(bQ1, sQ, n + 16)
#undef LOADB

    #pragma unroll
    for (int t = 0; t < TILES; ++t) {
        int jb = jb0 + t * 16;

        // A fragments: A[m=n, k=g*8+e] = cos/sin(k * x_n) (HW trig, revolutions).
        float tx = xv[t] * inv2pi;
        float cv[8], sv[8];
        #pragma unroll
        for (int e = 0; e < 8; ++e) {
            float tt = fract_((float)(g * 8 + e) * tx);
            cv[e] = __builtin_amdgcn_cosf(tt);
            sv[e] = __builtin_amdgcn_sinf(tt);
        }
        BF8 aC, aS;
        #pragma unroll
        for (int e = 0; e < 4; ++e) {
            aC.h[e] = __float22bfloat162_rn(float2{cv[2 * e], cv[2 * e + 1]});
            aS.h[e] = __float22bfloat162_rn(float2{sv[2 * e], sv[2 * e + 1]});
        }

        f32x4 z = {0.f, 0.f, 0.f, 0.f};
        f32x4 T0 = __builtin_amdgcn_mfma_f32_16x16x32_bf16(aC.v, bP0.v, z, 0, 0, 0);
        f32x4 T1 = __builtin_amdgcn_mfma_f32_16x16x32_bf16(aC.v, bP1.v, z, 0, 0, 0);
        f32x4 U0 = __builtin_amdgcn_mfma_f32_16x16x32_bf16(aS.v, bQ0.v, z, 0, 0, 0);
        f32x4 U1 = __builtin_amdgcn_mfma_f32_16x16x32_bf16(aS.v, bQ1.v, z, 0, 0, 0);

        // Epilogue: C[row=g*4+r, col=n] -> point g*4+r, l in {n, n+16}.
        float o[4];
        float l0 = (float)n, l1 = (float)(n + 16);
        #pragma unroll
        for (int r = 0; r < 4; ++r) {
            float ty = yv[t][r] * inv2pi;
            float c0 = __builtin_amdgcn_cosf(fract_(l0 * ty));
            float s0 = __builtin_amdgcn_sinf(fract_(l0 * ty));
            float c1 = __builtin_amdgcn_cosf(fract_(l1 * ty));
            float s1 = __builtin_amdgcn_sinf(fract_(l1 * ty));
            o[r] = fmaf(T0[r], c0, fmaf(U0[r], s0,
                   fmaf(T1[r], c1, U1[r] * s1)));
        }

        // Reduce over the 16 l-lanes (same g).
        #pragma unroll
        for (int m = 1; m < 16; m <<= 1) {
            #pragma unroll
            for (int r = 0; r < 4; ++r) o[r] += __shfl_xor(o[r], m, 64);
        }
        if (n == 0) {
            float4 res = make_float4(o[0], o[1], o[2], o[3]);
            *(float4*)&out[jb + g * 4] = res;
        }
    }
}

extern "C" void kernel_launch(void* const* d_in, const int* in_sizes, int n_in,
                              void* d_out, int out_size, void* d_ws, size_t ws_size,
                              hipStream_t stream) {
    const float* coef = (const float*)d_in[0];
    const float* x    = (const float*)d_in[1];
    const float* y    = (const float*)d_in[2];
    float* out = (float*)d_out;
    int M = in_sizes[1];
    int blocks = M / ((BLOCK / 64) * TILES * 16);   // 1024 for M=262144
    fouriergp_fused<<<blocks, BLOCK, 0, stream>>>(coef, x, y, out, M);
}

// Round 13
// 14.130 us; speedup vs baseline: 2.1161x; 1.0050x over previous
//
#include <hip/hip_runtime.h>
#include <hip/hip_bf16.h>
#include <math.h>

// out_j = sum_{k,l<NF} P[l,k] cos(k x_j) cos(l y_j) + Q[l,k] sin(k x_j) sin(l y_j)
// NF=24 truncation (spectral weight exp(-0.02 f^2) < 1e-5 beyond).
// Single fused kernel:
//  1) block-cooperative fold of the weighted 128x128 coefficient grid into
//     LDS P/Q[l][k] (zero-padded to 32x32; stride 68), coalesced mapping.
//  2) per 16-point tile: T[j,l] = sum_k P[l,k] cos(k x_j) via
//     mfma_f32_16x16x32_bf16. A-fragment trig via 4 HW trans + 7-step
//     FMA rotation recurrence (was 16 trans); epilogue trig direct.
//     16-lane shfl_xor reduce; lane n==0 stores a float4.

#define NF 24
#define LSTR 68            // LDS row stride in floats (16B-aligned)
#define BLOCK 256
#define TILES 4            // 16-pt tiles per wave -> 256 points per block

typedef __attribute__((ext_vector_type(8))) short bf16x8;
typedef __attribute__((ext_vector_type(4))) float f32x4;

union BF8 { bf16x8 v; __hip_bfloat162 h[4]; };

static __device__ __forceinline__ float fract_(float t) { return t - floorf(t); }

__global__ __launch_bounds__(BLOCK, 4)
void fouriergp_fused(const float* __restrict__ coef,
                     const float* __restrict__ xs,
                     const float* __restrict__ ys,
                     float* __restrict__ out, int M)
{
    __shared__ float sP[32 * LSTR];
    __shared__ float sQ[32 * LSTR];

    // ---- 1) cooperative fold into LDS (zero-padded to 32x32) ----
    // Coalesced mapping: lane index varies ll (column j).
    for (int t = threadIdx.x; t < 32 * 32; t += BLOCK) {
        int kk = t >> 5, ll = t & 31;
        float Pv = 0.f, Qv = 0.f;
        if (ll < NF && kk < NF) {
            float w = expf(-0.02f * (float)(kk * kk + ll * ll));
            int   iv[2]; float isg[2]; int ni;
            iv[0] = 64 - kk; isg[0] = (kk == 0) ? 0.f : -1.f; ni = 1;
            if (kk >= 1) { iv[1] = 64 + kk; isg[1] = 1.f; ni = 2; }
            int   jv[2]; float jsg[2]; int nj;
            jv[0] = 64 - ll; jsg[0] = (ll == 0) ? 0.f : -1.f; nj = 1;
            if (ll >= 1) { jv[1] = 64 + ll; jsg[1] = 1.f; nj = 2; }
            float s1 = 0.f, s2 = 0.f;
            for (int a = 0; a < ni; ++a) {
                for (int b = 0; b < nj; ++b) {
                    float c = coef[(iv[a] << 7) + jv[b]];
                    s1 += c;
                    s2 += isg[a] * jsg[b] * c;
                }
            }
            Pv = w * s1;
            Qv = -w * s2;
        }
        sP[ll * LSTR + kk] = Pv;
        sQ[ll * LSTR + kk] = Qv;
    }

    // ---- hoisted point loads (issue before the sync; used after) ----
    const float inv2pi = 0.15915494309189535f;
    int wid  = threadIdx.x >> 6;
    int lane = threadIdx.x & 63;
    int g    = lane >> 4;    // k-group (A/B), row-group (C)
    int n    = lane & 15;    // point index in A; l (column) index in B/C

    int jb0 = blockIdx.x * ((BLOCK / 64) * TILES * 16) + wid * (TILES * 16);
    float xv[TILES], yv[TILES][4];
    #pragma unroll
    for (int t = 0; t < TILES; ++t) {
        xv[t] = xs[jb0 + t * 16 + n];
        #pragma unroll
        for (int r = 0; r < 4; ++r)
            yv[t][r] = ys[jb0 + t * 16 + g * 4 + r];
    }

    __syncthreads();

    // B fragments: B[k=g*8+e, col=l] = P[l,k]; rows l = n and n+16.
    BF8 bP0, bP1, bQ0, bQ1;
#define LOADB(dst, arr, l_)                                             \
    {                                                                   \
        const float* bp = &arr[(l_) * LSTR + g * 8];                    \
        float4 v0 = *(const float4*)bp;                                 \
        float4 v1 = *(const float4*)(bp + 4);                           \
        dst.h[0] = __float22bfloat162_rn(float2{v0.x, v0.y});           \
        dst.h[1] = __float22bfloat162_rn(float2{v0.z, v0.w});           \
        dst.h[2] = __float22bfloat162_rn(float2{v1.x, v1.y});           \
        dst.h[3] = __float22bfloat162_rn(float2{v1.z, v1.w});           \
    }
    LOADB(bP0, sP, n)
    LOADB(bP1, sP, n + 16)
    LOADB(bQ0, sQ, n)
    LOADB(bQ1, sQ, n + 16)
#undef LOADB

    #pragma unroll
    for (int t = 0; t < TILES; ++t) {
        int jb = jb0 + t * 16;

        // A fragments: A[m=n, k=g*8+e] = cos/sin(k * x_n).
        // 4 HW trans (cos/sin of x and of 8g*x) + 7-step FMA rotation.
        float tx  = xv[t] * inv2pi;
        float txf = fract_(tx);
        float c1x = __builtin_amdgcn_cosf(txf);
        float s1x = __builtin_amdgcn_sinf(txf);
        float tb  = fract_((float)(g * 8) * tx);
        float cv[8], sv[8];
        cv[0] = __builtin_amdgcn_cosf(tb);
        sv[0] = __builtin_amdgcn_sinf(tb);
        #pragma unroll
        for (int e = 1; e < 8; ++e) {
            cv[e] = fmaf(cv[e - 1], c1x, -sv[e - 1] * s1x);
            sv[e] = fmaf(sv[e - 1], c1x,  cv[e - 1] * s1x);
        }
        BF8 aC, aS;
        #pragma unroll
        for (int e = 0; e < 4; ++e) {
            aC.h[e] = __float22bfloat162_rn(float2{cv[2 * e], cv[2 * e + 1]});
            aS.h[e] = __float22bfloat162_rn(float2{sv[2 * e], sv[2 * e + 1]});
        }

        f32x4 z = {0.f, 0.f, 0.f, 0.f};
        f32x4 T0 = __builtin_amdgcn_mfma_f32_16x16x32_bf16(aC.v, bP0.v, z, 0, 0, 0);
        f32x4 T1 = __builtin_amdgcn_mfma_f32_16x16x32_bf16(aC.v, bP1.v, z, 0, 0, 0);
        f32x4 U0 = __builtin_amdgcn_mfma_f32_16x16x32_bf16(aS.v, bQ0.v, z, 0, 0, 0);
        f32x4 U1 = __builtin_amdgcn_mfma_f32_16x16x32_bf16(aS.v, bQ1.v, z, 0, 0, 0);

        // Epilogue: C[row=g*4+r, col=n] -> point g*4+r, l in {n, n+16}.
        float o[4];
        float l0 = (float)n, l1 = (float)(n + 16);
        #pragma unroll
        for (int r = 0; r < 4; ++r) {
            float ty = yv[t][r] * inv2pi;
            float t0 = fract_(l0 * ty);
            float t1 = fract_(l1 * ty);
            float c0 = __builtin_amdgcn_cosf(t0);
            float s0 = __builtin_amdgcn_sinf(t0);
            float c1 = __builtin_amdgcn_cosf(t1);
            float s1 = __builtin_amdgcn_sinf(t1);
            o[r] = fmaf(T0[r], c0, fmaf(U0[r], s0,
                   fmaf(T1[r], c1, U1[r] * s1)));
        }

        // Reduce over the 16 l-lanes (same g).
        #pragma unroll
        for (int m = 1; m < 16; m <<= 1) {
            #pragma unroll
            for (int r = 0; r < 4; ++r) o[r] += __shfl_xor(o[r], m, 64);
        }
        if (n == 0) {
            float4 res = make_float4(o[0], o[1], o[2], o[3]);
            *(float4*)&out[jb + g * 4] = res;
        }
    }
}

extern "C" void kernel_launch(void* const* d_in, const int* in_sizes, int n_in,
                              void* d_out, int out_size, void* d_ws, size_t ws_size,
                              hipStream_t stream) {
    const float* coef = (const float*)d_in[0];
    const float* x    = (const float*)d_in[1];
    const float* y    = (const float*)d_in[2];
    float* out = (float*)d_out;
    int M = in_sizes[1];
    int blocks = M / ((BLOCK / 64) * TILES * 16);   // 1024 for M=262144
    fouriergp_fused<<<blocks, BLOCK, 0, stream>>>(coef, x, y, out, M);
}